// Round 9
// baseline (360.566 us; speedup 1.0000x reference)
//
#include <hip/hip_runtime.h>

// Problem constants
#define BB 8
#define TT 1024
#define NH 8
#define HD 64
#define QT 128   // q rows per attention block

typedef unsigned short u16;
typedef __attribute__((ext_vector_type(8))) short bf16x8;
typedef __attribute__((ext_vector_type(16))) float f32x16;

__device__ __forceinline__ float bf2f(u16 s) {
    union { unsigned u; float f; } v; v.u = ((unsigned)s) << 16; return v.f;
}
__device__ __forceinline__ u16 f2bf(float f) {
    union { float f; unsigned u; } v; v.f = f;
    unsigned r = (v.u + 0x7FFFu + ((v.u >> 16) & 1u)) >> 16;
    return (u16)r;
}

#define MFMA(a, b, c) __builtin_amdgcn_mfma_f32_32x32x16_bf16((a), (b), (c), 0, 0, 0)

// ---------------------------------------------------------------------------
// Flat fp32 -> bf16 for x (4,194,304 elems) and rel_emb (65,600 elems).
// ---------------------------------------------------------------------------
#define NX4 1048576   // x float4 chunks
#define NR4 16400     // rel float4 chunks
__global__ void cvt_misc(const float* __restrict__ x, const float* __restrict__ rel,
                         u16* __restrict__ xb, u16* __restrict__ relb)
{
    size_t i = (size_t)blockIdx.x * 256 + threadIdx.x;
    const float* src; u16* dst;
    if (i < NX4) { src = x; dst = xb; }
    else {
        i -= NX4;
        if (i >= NR4) return;
        src = rel; dst = relb;
    }
    float4 f = *(const float4*)(src + i * 4);
    ushort4 o;
    o.x = f2bf(f.x); o.y = f2bf(f.y); o.z = f2bf(f.z); o.w = f2bf(f.w);
    *(ushort4*)(dst + i * 4) = o;
}

// ---------------------------------------------------------------------------
// Transpose W [512, N] fp32 -> W^T [N, 512] bf16 (Wq, Wkv, Wout in one grid).
// WqT and WkvT are laid out contiguously (WT_all[1536][512]).
// ---------------------------------------------------------------------------
__global__ __launch_bounds__(256) void cvt_wT(
    const float* __restrict__ Wq, const float* __restrict__ Wkv,
    const float* __restrict__ Wout,
    u16* __restrict__ WqT, u16* __restrict__ WkvT, u16* __restrict__ WoutT)
{
    __shared__ float tile[64][65];
    int bid = blockIdx.x;
    const float* W; u16* Wt; int N, kt, ct;
    if (bid < 64)       { W = Wq;   Wt = WqT;   N = 512;  kt = (bid >> 3) * 64; ct = (bid & 7) * 64; }
    else if (bid < 192) { bid -= 64;  W = Wkv;  Wt = WkvT; N = 1024; kt = (bid >> 4) * 64; ct = (bid & 15) * 64; }
    else                { bid -= 192; W = Wout; Wt = WoutT; N = 512;  kt = (bid >> 3) * 64; ct = (bid & 7) * 64; }

    const int tid = threadIdx.x;
#pragma unroll
    for (int i = 0; i < 16; i++) {
        int e = tid + i * 256;
        int r = e >> 6, c = e & 63;
        tile[r][c] = W[(size_t)(kt + r) * N + ct + c];
    }
    __syncthreads();
#pragma unroll
    for (int i = 0; i < 16; i++) {
        int e = tid + i * 256;
        int rr = e >> 6, cc = e & 63;   // output row = original col
        Wt[(size_t)(ct + rr) * 512 + kt + cc] = f2bf(tile[cc][rr]);
    }
}

// ---------------------------------------------------------------------------
// Fused qkv projection (bf16 MFMA, zero LDS), 64x64 per wave.
// Block = 4 waves in 2x2 -> 128x128 tile. Grid (64, 12). MFMA:VMEM = 1:1.
// B given transposed: WT_all[1536][512]. c<512: q scaled 0.125 -> [b,h,t,d];
// 512..1024: k -> [b,h,t,d]; 1024..1536: v TRANSPOSED -> [b,h,d,t].
// ---------------------------------------------------------------------------
__global__ __launch_bounds__(256) void gemm_qkv(
    const u16* __restrict__ A, const u16* __restrict__ Bt,
    const float* __restrict__ bq, const float* __restrict__ bkv,
    u16* __restrict__ oq, u16* __restrict__ ok, u16* __restrict__ ov)
{
    const int tid = threadIdx.x;
    const int lane = tid & 63, w = tid >> 6;
    const int l31 = lane & 31, lh = lane >> 5;
    const int wr = w & 1, wc = w >> 1;
    const int row0 = blockIdx.x * 128 + 64 * wr;
    const int c0g  = blockIdx.y * 128 + 64 * wc;

    const u16* ap0 = A  + (size_t)(row0 + l31) * 512 + 8 * lh;
    const u16* ap1 = ap0 + (size_t)32 * 512;
    const u16* bp0 = Bt + (size_t)(c0g + l31) * 512 + 8 * lh;
    const u16* bp1 = bp0 + (size_t)32 * 512;

    f32x16 acc[2][2];
#pragma unroll
    for (int i = 0; i < 2; i++)
#pragma unroll
        for (int j = 0; j < 2; j++)
#pragma unroll
            for (int e = 0; e < 16; e++) acc[i][j][e] = 0.f;

#pragma unroll 4
    for (int ks = 0; ks < 32; ks++) {
        bf16x8 a0 = *(const bf16x8*)(ap0 + 16 * ks);
        bf16x8 a1 = *(const bf16x8*)(ap1 + 16 * ks);
        bf16x8 b0 = *(const bf16x8*)(bp0 + 16 * ks);
        bf16x8 b1 = *(const bf16x8*)(bp1 + 16 * ks);
        acc[0][0] = MFMA(a0, b0, acc[0][0]);
        acc[0][1] = MFMA(a0, b1, acc[0][1]);
        acc[1][0] = MFMA(a1, b0, acc[1][0]);
        acc[1][1] = MFMA(a1, b1, acc[1][1]);
    }

    const int rbase = 4 * lh;
#pragma unroll
    for (int ri = 0; ri < 2; ri++) {
#pragma unroll
        for (int ci = 0; ci < 2; ci++) {
            const int r0 = row0 + 32 * ri;
            const int gc = c0g + 32 * ci + l31;
            if (gc < 512) {            // q (scaled)
                const float bv = bq[gc];
                const int h = gc >> 6, d = gc & 63;
#pragma unroll
                for (int rg = 0; rg < 16; rg++) {
                    int gr = r0 + (rg & 3) + 8 * (rg >> 2) + rbase;
                    int b = gr >> 10, t = gr & 1023;
                    oq[(((size_t)b * NH + h) * TT + t) * HD + d] =
                        f2bf((acc[ri][ci][rg] + bv) * 0.125f);
                }
            } else if (gc < 1024) {    // k
                const float bv = bkv[gc - 512];
                const int h = (gc - 512) >> 6, d = gc & 63;
#pragma unroll
                for (int rg = 0; rg < 16; rg++) {
                    int gr = r0 + (rg & 3) + 8 * (rg >> 2) + rbase;
                    int b = gr >> 10, t = gr & 1023;
                    ok[(((size_t)b * NH + h) * TT + t) * HD + d] =
                        f2bf(acc[ri][ci][rg] + bv);
                }
            } else {                   // v, transposed [b,h,d,t]
                const float bv = bkv[gc - 512];
                const int vcol = gc - 1024;
                const int h = vcol >> 6, d = vcol & 63;
                const int b = r0 >> 10;
                const int t0 = (r0 & 1023) + rbase;
                size_t base = (((size_t)b * NH + h) * HD + d) * TT;
#pragma unroll
                for (int g = 0; g < 4; g++) {
                    ushort4 p;
                    p.x = f2bf(acc[ri][ci][4 * g + 0] + bv);
                    p.y = f2bf(acc[ri][ci][4 * g + 1] + bv);
                    p.z = f2bf(acc[ri][ci][4 * g + 2] + bv);
                    p.w = f2bf(acc[ri][ci][4 * g + 3] + bv);
                    *(ushort4*)&ov[base + t0 + 8 * g] = p;
                }
            }
        }
    }
}

// ---------------------------------------------------------------------------
// Out projection: out = a[8192,512] @ Wout + bout, fp32 result.
// Wave = 32 rows x 32 cols -> 4096 waves (16/CU). Grid (64, 16).
// ---------------------------------------------------------------------------
__global__ __launch_bounds__(256) void gemm_out(
    const u16* __restrict__ A, const u16* __restrict__ Bt,
    const float* __restrict__ bias, float* __restrict__ of)
{
    const int tid = threadIdx.x;
    const int lane = tid & 63, w = tid >> 6;
    const int l31 = lane & 31, lh = lane >> 5;
    const int row0 = blockIdx.x * 128 + 32 * w;
    const int c0 = blockIdx.y * 32;

    const u16* ap  = A  + (size_t)(row0 + l31) * 512 + 8 * lh;
    const u16* bp0 = Bt + (size_t)(c0 + l31) * 512 + 8 * lh;

    f32x16 acc0;
#pragma unroll
    for (int i = 0; i < 16; i++) acc0[i] = 0.f;

#pragma unroll 4
    for (int ks = 0; ks < 32; ks++) {
        bf16x8 a  = *(const bf16x8*)(ap  + 16 * ks);
        bf16x8 b0 = *(const bf16x8*)(bp0 + 16 * ks);
        acc0 = MFMA(a, b0, acc0);
    }

    const int rbase = 4 * lh;
    const float bv0 = bias[c0 + l31];
#pragma unroll
    for (int rg = 0; rg < 16; rg++) {
        int gr = row0 + (rg & 3) + 8 * (rg >> 2) + rbase;
        of[(size_t)gr * 512 + c0 + l31] = acc0[rg] + bv0;
    }
}

// ---------------------------------------------------------------------------
// MFMA flash attention, rel-pos via skew gather, barrier-free, 2-way K-split.
// Grid (64, 16): bx = bh (XCD-clustered — proven R8: FETCH 70->16 MB).
// by = nt*2 + sp; wave w owns q-rows [32w,32w+32); split sp does m-tiles
// [8sp,8sp+8). Writes UNNORMALIZED bf16 O partials + fp32 row-sums.
// R9 changes (internal only):
//  - G band spilled TRANSPOSED GwT[j][r] (stride 36 u16): C-layout reg quads
//    are consecutive rows -> 12 ds_write_b64 instead of 48 scalar writes.
//    Stride 36: 8B-aligned b64 stores, <=2-way banks on spill and gather.
//  - __launch_bounds__(256,3): cap regs at ~170 for 3 waves/SIMD (R6/R8 ran
//    at ~188 total -> 2 waves/SIMD, the occupancy cliff behind 21%).
// LDS: per-wave GwT 96x36 u16 + Pb 32x72 u16 = 11.25 KB -> 45 KB/block.
// ---------------------------------------------------------------------------
__global__ __launch_bounds__(256, 3) void attn_mfma(
    const u16* __restrict__ q_ws, const u16* __restrict__ k_ws,
    const u16* __restrict__ v_ws, const u16* __restrict__ relb,
    u16* __restrict__ Opart, float* __restrict__ Lpart)
{
    __shared__ __align__(16) u16 GwTs[4][96 * 36];   // per-wave transposed G band
    __shared__ __align__(16) u16 Pbs[4][32 * 72];    // per-wave P tile

    const int tid  = threadIdx.x;
    const int lane = tid & 63;
    const int w    = tid >> 6;
    const int l31  = lane & 31;
    const int lh   = lane >> 5;
    const int bh   = blockIdx.x;
    const int nt   = blockIdx.y >> 1;
    const int sp   = blockIdx.y & 1;
    const int n0   = nt * QT;

    // Q A-fragments (rows n0+32w+l31), held in registers for all m-tiles
    bf16x8 a_q[4];
    {
        const u16* qp = q_ws + (((size_t)bh * TT) + n0 + 32 * w + l31) * HD + 8 * lh;
#pragma unroll
        for (int ks = 0; ks < 4; ks++)
            a_q[ks] = *(const bf16x8*)(qp + 16 * ks);
    }

    f32x16 O0, O1;
    float li[16];
#pragma unroll
    for (int i = 0; i < 16; i++) { O0[i] = 0.f; O1[i] = 0.f; li[i] = 0.f; }

    u16* GwT = GwTs[w];
    u16* Pb  = Pbs[w];
    const int rbase = 4 * lh;

    for (int mt = 8 * sp; mt < 8 * sp + 8; mt++) {
        const int m0 = mt * 64;
        const u16* kb = k_ws + ((size_t)bh * TT + m0) * HD;

        // ---- S = Q K^T  (B-frags straight from global: 8 contiguous d)
        f32x16 S0, S1;
#pragma unroll
        for (int i = 0; i < 16; i++) { S0[i] = 0.f; S1[i] = 0.f; }
#pragma unroll
        for (int ks = 0; ks < 4; ks++) {
            const int doff = 16 * ks + 8 * lh;
            bf16x8 b0 = *(const bf16x8*)(kb + (size_t)l31 * HD + doff);
            bf16x8 b1 = *(const bf16x8*)(kb + (size_t)(l31 + 32) * HD + doff);
            S0 = MFMA(a_q[ks], b0, S0);
            S1 = MFMA(a_q[ks], b1, S1);
        }

        // ---- G = Q R^T (3 col-tiles), spill TRANSPOSED via ds_write_b64
        const int pb = n0 - m0 + 449 + 32 * w;
#pragma unroll
        for (int gt = 0; gt < 3; gt++) {
            f32x16 g;
#pragma unroll
            for (int i = 0; i < 16; i++) g[i] = 0.f;
            int p = pb + 32 * gt + l31;
            p = p < 0 ? 0 : (p > 1024 ? 1024 : p);
            const u16* rb = relb + (size_t)p * HD;
#pragma unroll
            for (int ks = 0; ks < 4; ks++) {
                bf16x8 br = *(const bf16x8*)(rb + 16 * ks + 8 * lh);
                g = MFMA(a_q[ks], br, g);
            }
            const int jp = 32 * gt + l31;
#pragma unroll
            for (int grp = 0; grp < 4; grp++) {
                // reg quad 4*grp..4*grp+3 = rows (8*grp+rbase)..(+3), consecutive
                ushort4 pk;
                pk.x = f2bf(g[4 * grp + 0]);
                pk.y = f2bf(g[4 * grp + 1]);
                pk.z = f2bf(g[4 * grp + 2]);
                pk.w = f2bf(g[4 * grp + 3]);
                *(ushort4*)&GwT[jp * 36 + 8 * grp + rbase] = pk;
            }
        }

        // ---- skew gather from GwT[j][r] (wave-private, per-wave DS ordering)
#pragma unroll
        for (int rg = 0; rg < 16; rg++) {
            int r = (rg & 3) + 8 * (rg >> 2) + rbase;
            int j0 = r - l31 + 63;
            S0[rg] += bf2f(GwT[j0 * 36 + r]);
            S1[rg] += bf2f(GwT[(j0 - 32) * 36 + r]);
        }

        // ---- streaming softmax: raw exp, per-lane partial row-sums
#pragma unroll
        for (int rg = 0; rg < 16; rg++) {
            float e0 = __expf(S0[rg]);
            float e1 = __expf(S1[rg]);
            S0[rg] = e0; S1[rg] = e1;
            li[rg] += e0 + e1;
        }

        // ---- P -> LDS bf16 (swizzled, wave-private)
#pragma unroll
        for (int rg = 0; rg < 16; rg++) {
            int r = (rg & 3) + 8 * (rg >> 2) + rbase;
            int ca = l31, cb = l31 + 32;
            Pb[r * 72 + (((ca >> 3) ^ (r & 7)) * 8) + (ca & 7)] = f2bf(S0[rg]);
            Pb[r * 72 + (((cb >> 3) ^ (r & 7)) * 8) + (cb & 7)] = f2bf(S1[rg]);
        }

        // ---- O += P V  (V B-frags straight from global: 8 contiguous t)
        const u16* vb = v_ws + (size_t)bh * HD * TT + m0;
#pragma unroll
        for (int ms = 0; ms < 4; ms++) {
            const int mg = 2 * ms + lh;
            bf16x8 a_p = *(const bf16x8*)&Pb[l31 * 72 + ((mg ^ (l31 & 7)) * 8)];
            bf16x8 b0 = *(const bf16x8*)(vb + (size_t)l31 * TT + mg * 8);
            bf16x8 b1 = *(const bf16x8*)(vb + (size_t)(l31 + 32) * TT + mg * 8);
            O0 = MFMA(a_p, b0, O0);
            O1 = MFMA(a_p, b1, O1);
        }
    }

    // ---- reduce li partials across the 32 lanes holding each row
#pragma unroll
    for (int rg = 0; rg < 16; rg++) {
        float rs = li[rg];
        rs += __shfl_xor(rs, 1);
        rs += __shfl_xor(rs, 2);
        rs += __shfl_xor(rs, 4);
        rs += __shfl_xor(rs, 8);
        rs += __shfl_xor(rs, 16);
        li[rg] = rs;
    }

    // ---- write bf16 O partials: Opart[s][bh][n][d]; fp32 Lpart[s][bh][n]
    u16* op = Opart + (((size_t)sp * 64 + bh) * TT + n0 + 32 * w) * HD;
#pragma unroll
    for (int rg = 0; rg < 16; rg++) {
        int r = (rg & 3) + 8 * (rg >> 2) + rbase;
        op[(size_t)r * HD + l31]      = f2bf(O0[rg]);
        op[(size_t)r * HD + 32 + l31] = f2bf(O1[rg]);
    }
    if (l31 == 0) {
        float* lp = Lpart + ((size_t)sp * 64 + bh) * TT + n0 + 32 * w;
#pragma unroll
        for (int rg = 0; rg < 16; rg++) {
            int r = (rg & 3) + 8 * (rg >> 2) + rbase;
            lp[r] = li[rg];
        }
    }
}

// ---------------------------------------------------------------------------
// Combine the 2 attention splits: a = (O0+O1)/(l0+l1) -> bf16 [b,t,h*64+d].
// 256 threads = 16 rows x 16 threads (4 d each). Grid: 65536/16 = 4096.
// ---------------------------------------------------------------------------
__global__ __launch_bounds__(256) void attn_combine(
    const u16* __restrict__ Opart, const float* __restrict__ Lpart,
    u16* __restrict__ a_out)
{
    const int tid = threadIdx.x;
    const int row = blockIdx.x * 16 + (tid >> 4);   // 0..65535 over [bh][t]
    const int dq  = (tid & 15) * 4;
    const int bh = row >> 10, n = row & 1023;

    const size_t OS = (size_t)64 * TT * HD;   // split stride (elems)
    size_t o0 = ((size_t)bh * TT + n) * HD + dq;
    ushort4 p0 = *(const ushort4*)(Opart + o0);
    ushort4 p1 = *(const ushort4*)(Opart + OS + o0);
    float l = Lpart[(size_t)bh * TT + n] + Lpart[(size_t)64 * TT + bh * TT + n];
    float inv = 1.0f / l;

    const int b = bh >> 3, h = bh & 7;
    ushort4 o;
    o.x = f2bf((bf2f(p0.x) + bf2f(p1.x)) * inv);
    o.y = f2bf((bf2f(p0.y) + bf2f(p1.y)) * inv);
    o.z = f2bf((bf2f(p0.z) + bf2f(p1.z)) * inv);
    o.w = f2bf((bf2f(p0.w) + bf2f(p1.w)) * inv);
    *(ushort4*)&a_out[((size_t)b * TT + n) * 512 + h * HD + dq] = o;
}

// ---------------------------------------------------------------------------
// Workspace layout (43 MB total — inside the PROVEN 44 MB envelope).
//   [ 0, 8)  q_wsb (B-C)  /  a_wsb (D-E)
//   [ 8,16)  k_wsb
//   [16,24)  v_wsb
//   [24,32)  x_bf (A-B)   /  Opart low half (C-D)
//   [32,40)  Opart high half
//   [40,40.5) Lpart     [40.5,41) relb
//   [41,42.5) WT_all    [42.5,43) WoutT
// ---------------------------------------------------------------------------
extern "C" void kernel_launch(void* const* d_in, const int* in_sizes, int n_in,
                              void* d_out, int out_size, void* d_ws, size_t ws_size,
                              hipStream_t stream)
{
    const float* x    = (const float*)d_in[0];
    const float* Wq   = (const float*)d_in[1];
    const float* bq   = (const float*)d_in[2];
    const float* Wkv  = (const float*)d_in[3];
    const float* bkv  = (const float*)d_in[4];
    const float* Wout = (const float*)d_in[5];
    const float* bout = (const float*)d_in[6];
    const float* rel  = (const float*)d_in[7];
    float* out = (float*)d_out;

    char* ws = (char*)d_ws;
    const size_t MB = 1024 * 1024;
    u16*   q_wsb  = (u16*)(ws);                           // 8 MB [b,h,t,d]
    u16*   a_wsb  = (u16*)(ws);                           // reuse (D-E)
    u16*   k_wsb  = (u16*)(ws + 8 * MB);                  // 8 MB [b,h,t,d]
    u16*   v_wsb  = (u16*)(ws + 16 * MB);                 // 8 MB [b,h,d,t]
    u16*   x_bf   = (u16*)(ws + 24 * MB);                 // 8 MB [8192,512]
    u16*   Opart  = (u16*)(ws + 24 * MB);                 // 16 MB reuse (C-D)
    float* Lpart  = (float*)(ws + 40 * MB);               // 512 KB
    u16*   relb   = (u16*)(ws + 40 * MB + 512 * 1024);    // 128 KB
    u16*   WT_all = (u16*)(ws + 41 * MB);                 // 1.5 MB [1536,512]
    u16*   WoutT  = (u16*)(ws + 42 * MB + 512 * 1024);    // 512 KB [512,512]

    // A: dtype conversions
    cvt_misc<<<(NX4 + NR4 + 255) / 256, 256, 0, stream>>>(x, rel, x_bf, relb);
    cvt_wT<<<256, 256, 0, stream>>>(Wq, Wkv, Wout, WT_all, WT_all + 512 * 512, WoutT);

    // B: fused qkv projection, 64x64/wave (768 blocks = 3/CU)
    gemm_qkv<<<dim3(64, 12), 256, 0, stream>>>(
        x_bf, WT_all, bq, bkv, q_wsb, k_wsb, v_wsb);

    // C: attention, 2-way K-split, XCD-clustered grid (1024 blocks)
    attn_mfma<<<dim3(64, 16), 256, 0, stream>>>(
        q_wsb, k_wsb, v_wsb, relb, Opart, Lpart);

    // D: combine splits
    attn_combine<<<4096, 256, 0, stream>>>(Opart, Lpart, a_wsb);

    // E: out projection (4096 waves = 16/CU)
    gemm_out<<<dim3(64, 16), 256, 0, stream>>>(a_wsb, WoutT, bout, out);
}

// Round 10
// 291.047 us; speedup vs baseline: 1.2389x; 1.2389x over previous
//
#include <hip/hip_runtime.h>

// Problem constants
#define BB 8
#define TT 1024
#define NH 8
#define HD 64
#define QT 128   // q rows per attention block

typedef unsigned short u16;
typedef __attribute__((ext_vector_type(8))) short bf16x8;
typedef __attribute__((ext_vector_type(16))) float f32x16;

__device__ __forceinline__ float bf2f(u16 s) {
    union { unsigned u; float f; } v; v.u = ((unsigned)s) << 16; return v.f;
}
__device__ __forceinline__ u16 f2bf(float f) {
    union { float f; unsigned u; } v; v.f = f;
    unsigned r = (v.u + 0x7FFFu + ((v.u >> 16) & 1u)) >> 16;
    return (u16)r;
}

#define MFMA(a, b, c) __builtin_amdgcn_mfma_f32_32x32x16_bf16((a), (b), (c), 0, 0, 0)

// ---------------------------------------------------------------------------
// Flat fp32 -> bf16 for x (4,194,304 elems) and rel_emb (65,600 elems).
// ---------------------------------------------------------------------------
#define NX4 1048576   // x float4 chunks
#define NR4 16400     // rel float4 chunks
__global__ void cvt_misc(const float* __restrict__ x, const float* __restrict__ rel,
                         u16* __restrict__ xb, u16* __restrict__ relb)
{
    size_t i = (size_t)blockIdx.x * 256 + threadIdx.x;
    const float* src; u16* dst;
    if (i < NX4) { src = x; dst = xb; }
    else {
        i -= NX4;
        if (i >= NR4) return;
        src = rel; dst = relb;
    }
    float4 f = *(const float4*)(src + i * 4);
    ushort4 o;
    o.x = f2bf(f.x); o.y = f2bf(f.y); o.z = f2bf(f.z); o.w = f2bf(f.w);
    *(ushort4*)(dst + i * 4) = o;
}

// ---------------------------------------------------------------------------
// Transpose W [512, N] fp32 -> W^T [N, 512] bf16 (Wq, Wkv, Wout in one grid).
// WqT and WkvT are laid out contiguously (WT_all[1536][512]).
// ---------------------------------------------------------------------------
__global__ __launch_bounds__(256) void cvt_wT(
    const float* __restrict__ Wq, const float* __restrict__ Wkv,
    const float* __restrict__ Wout,
    u16* __restrict__ WqT, u16* __restrict__ WkvT, u16* __restrict__ WoutT)
{
    __shared__ float tile[64][65];
    int bid = blockIdx.x;
    const float* W; u16* Wt; int N, kt, ct;
    if (bid < 64)       { W = Wq;   Wt = WqT;   N = 512;  kt = (bid >> 3) * 64; ct = (bid & 7) * 64; }
    else if (bid < 192) { bid -= 64;  W = Wkv;  Wt = WkvT; N = 1024; kt = (bid >> 4) * 64; ct = (bid & 15) * 64; }
    else                { bid -= 192; W = Wout; Wt = WoutT; N = 512;  kt = (bid >> 3) * 64; ct = (bid & 7) * 64; }

    const int tid = threadIdx.x;
#pragma unroll
    for (int i = 0; i < 16; i++) {
        int e = tid + i * 256;
        int r = e >> 6, c = e & 63;
        tile[r][c] = W[(size_t)(kt + r) * N + ct + c];
    }
    __syncthreads();
#pragma unroll
    for (int i = 0; i < 16; i++) {
        int e = tid + i * 256;
        int rr = e >> 6, cc = e & 63;   // output row = original col
        Wt[(size_t)(ct + rr) * 512 + kt + cc] = f2bf(tile[cc][rr]);
    }
}

// ---------------------------------------------------------------------------
// Fused qkv projection (bf16 MFMA, zero LDS), 64x64 per wave (proven R9:
// rest-time 182 -> 158 us vs the 32x64 version). Block = 4 waves in 2x2 ->
// 128x128 tile. Grid (64, 12). MFMA:VMEM = 1:1.
// B given transposed: WT_all[1536][512]. c<512: q scaled 0.125 -> [b,h,t,d];
// 512..1024: k -> [b,h,t,d]; 1024..1536: v TRANSPOSED -> [b,h,d,t].
// ---------------------------------------------------------------------------
__global__ __launch_bounds__(256) void gemm_qkv(
    const u16* __restrict__ A, const u16* __restrict__ Bt,
    const float* __restrict__ bq, const float* __restrict__ bkv,
    u16* __restrict__ oq, u16* __restrict__ ok, u16* __restrict__ ov)
{
    const int tid = threadIdx.x;
    const int lane = tid & 63, w = tid >> 6;
    const int l31 = lane & 31, lh = lane >> 5;
    const int wr = w & 1, wc = w >> 1;
    const int row0 = blockIdx.x * 128 + 64 * wr;
    const int c0g  = blockIdx.y * 128 + 64 * wc;

    const u16* ap0 = A  + (size_t)(row0 + l31) * 512 + 8 * lh;
    const u16* ap1 = ap0 + (size_t)32 * 512;
    const u16* bp0 = Bt + (size_t)(c0g + l31) * 512 + 8 * lh;
    const u16* bp1 = bp0 + (size_t)32 * 512;

    f32x16 acc[2][2];
#pragma unroll
    for (int i = 0; i < 2; i++)
#pragma unroll
        for (int j = 0; j < 2; j++)
#pragma unroll
            for (int e = 0; e < 16; e++) acc[i][j][e] = 0.f;

#pragma unroll 4
    for (int ks = 0; ks < 32; ks++) {
        bf16x8 a0 = *(const bf16x8*)(ap0 + 16 * ks);
        bf16x8 a1 = *(const bf16x8*)(ap1 + 16 * ks);
        bf16x8 b0 = *(const bf16x8*)(bp0 + 16 * ks);
        bf16x8 b1 = *(const bf16x8*)(bp1 + 16 * ks);
        acc[0][0] = MFMA(a0, b0, acc[0][0]);
        acc[0][1] = MFMA(a0, b1, acc[0][1]);
        acc[1][0] = MFMA(a1, b0, acc[1][0]);
        acc[1][1] = MFMA(a1, b1, acc[1][1]);
    }

    const int rbase = 4 * lh;
#pragma unroll
    for (int ri = 0; ri < 2; ri++) {
#pragma unroll
        for (int ci = 0; ci < 2; ci++) {
            const int r0 = row0 + 32 * ri;
            const int gc = c0g + 32 * ci + l31;
            if (gc < 512) {            // q (scaled)
                const float bv = bq[gc];
                const int h = gc >> 6, d = gc & 63;
#pragma unroll
                for (int rg = 0; rg < 16; rg++) {
                    int gr = r0 + (rg & 3) + 8 * (rg >> 2) + rbase;
                    int b = gr >> 10, t = gr & 1023;
                    oq[(((size_t)b * NH + h) * TT + t) * HD + d] =
                        f2bf((acc[ri][ci][rg] + bv) * 0.125f);
                }
            } else if (gc < 1024) {    // k
                const float bv = bkv[gc - 512];
                const int h = (gc - 512) >> 6, d = gc & 63;
#pragma unroll
                for (int rg = 0; rg < 16; rg++) {
                    int gr = r0 + (rg & 3) + 8 * (rg >> 2) + rbase;
                    int b = gr >> 10, t = gr & 1023;
                    ok[(((size_t)b * NH + h) * TT + t) * HD + d] =
                        f2bf(acc[ri][ci][rg] + bv);
                }
            } else {                   // v, transposed [b,h,d,t]
                const float bv = bkv[gc - 512];
                const int vcol = gc - 1024;
                const int h = vcol >> 6, d = vcol & 63;
                const int b = r0 >> 10;
                const int t0 = (r0 & 1023) + rbase;
                size_t base = (((size_t)b * NH + h) * HD + d) * TT;
#pragma unroll
                for (int g = 0; g < 4; g++) {
                    ushort4 p;
                    p.x = f2bf(acc[ri][ci][4 * g + 0] + bv);
                    p.y = f2bf(acc[ri][ci][4 * g + 1] + bv);
                    p.z = f2bf(acc[ri][ci][4 * g + 2] + bv);
                    p.w = f2bf(acc[ri][ci][4 * g + 3] + bv);
                    *(ushort4*)&ov[base + t0 + 8 * g] = p;
                }
            }
        }
    }
}

// ---------------------------------------------------------------------------
// Out projection: out = a[8192,512] @ Wout + bout, fp32 result.
// Wave = 32 rows x 32 cols -> 4096 waves (16/CU). Grid (64, 16).
// ---------------------------------------------------------------------------
__global__ __launch_bounds__(256) void gemm_out(
    const u16* __restrict__ A, const u16* __restrict__ Bt,
    const float* __restrict__ bias, float* __restrict__ of)
{
    const int tid = threadIdx.x;
    const int lane = tid & 63, w = tid >> 6;
    const int l31 = lane & 31, lh = lane >> 5;
    const int row0 = blockIdx.x * 128 + 32 * w;
    const int c0 = blockIdx.y * 32;

    const u16* ap  = A  + (size_t)(row0 + l31) * 512 + 8 * lh;
    const u16* bp0 = Bt + (size_t)(c0 + l31) * 512 + 8 * lh;

    f32x16 acc0;
#pragma unroll
    for (int i = 0; i < 16; i++) acc0[i] = 0.f;

#pragma unroll 4
    for (int ks = 0; ks < 32; ks++) {
        bf16x8 a  = *(const bf16x8*)(ap  + 16 * ks);
        bf16x8 b0 = *(const bf16x8*)(bp0 + 16 * ks);
        acc0 = MFMA(a, b0, acc0);
    }

    const int rbase = 4 * lh;
    const float bv0 = bias[c0 + l31];
#pragma unroll
    for (int rg = 0; rg < 16; rg++) {
        int gr = row0 + (rg & 3) + 8 * (rg >> 2) + rbase;
        of[(size_t)gr * 512 + c0 + l31] = acc0[rg] + bv0;
    }
}

// ---------------------------------------------------------------------------
// MFMA flash attention, rel-pos via skew gather, barrier-free, NO K-split
// (R10: K-split reverted — R6/R8 showed it neutral; residency is register-
// limited at ~2 blocks/CU, so grid 512 = 2/CU already saturates, and
// dropping the split deletes the combine pass + 32 MB Opart round-trip).
// Grid (64, 8): bx = bh (XCD-clustered, proven R8: FETCH 70->16 MB),
// by = nt. Block: 256 = 4 waves; wave w owns q-rows [32w,32w+32).
// R3-proven body: 16 m-tiles, G spill row-major stride 104 (R9's stride-36
// transpose TRIPLED bank conflicts — reverted), raw-exp streaming softmax,
// direct bf16 output with in-kernel normalize.
// NO __launch_bounds__ min-waves (R9: forcing 3 waves/SIMD -> scratch spills,
// +50 MB HBM traffic, 135->202 us).
// LDS: per-wave 32x104 u16 G/P buffer (26.6 KB).
// ---------------------------------------------------------------------------
__global__ __launch_bounds__(256) void attn_mfma(
    const u16* __restrict__ q_ws, const u16* __restrict__ k_ws,
    const u16* __restrict__ v_ws, const u16* __restrict__ relb,
    u16* __restrict__ attn_out)
{
    __shared__ __align__(16) u16 GPs[4][32 * 104];   // per-wave G band / P tile

    const int tid  = threadIdx.x;
    const int lane = tid & 63;
    const int w    = tid >> 6;
    const int l31  = lane & 31;
    const int lh   = lane >> 5;
    const int bh   = blockIdx.x;
    const int n0   = blockIdx.y * QT;

    // Q A-fragments (rows n0+32w+l31), held in registers for all 16 m-tiles
    bf16x8 a_q[4];
    {
        const u16* qp = q_ws + (((size_t)bh * TT) + n0 + 32 * w + l31) * HD + 8 * lh;
#pragma unroll
        for (int ks = 0; ks < 4; ks++)
            a_q[ks] = *(const bf16x8*)(qp + 16 * ks);
    }

    f32x16 O0, O1;
    float li[16];
#pragma unroll
    for (int i = 0; i < 16; i++) { O0[i] = 0.f; O1[i] = 0.f; li[i] = 0.f; }

    u16* Gw = GPs[w];
    const int rbase = 4 * lh;

    for (int mt = 0; mt < 16; mt++) {
        const int m0 = mt * 64;
        const u16* kb = k_ws + ((size_t)bh * TT + m0) * HD;

        // ---- S = Q K^T  (B-frags straight from global: 8 contiguous d)
        f32x16 S0, S1;
#pragma unroll
        for (int i = 0; i < 16; i++) { S0[i] = 0.f; S1[i] = 0.f; }
#pragma unroll
        for (int ks = 0; ks < 4; ks++) {
            const int doff = 16 * ks + 8 * lh;
            bf16x8 b0 = *(const bf16x8*)(kb + (size_t)l31 * HD + doff);
            bf16x8 b1 = *(const bf16x8*)(kb + (size_t)(l31 + 32) * HD + doff);
            S0 = MFMA(a_q[ks], b0, S0);
            S1 = MFMA(a_q[ks], b1, S1);
        }

        // ---- G = Q R^T (3 col-tiles; rel B-frags straight from global)
        const int pb = n0 - m0 + 449 + 32 * w;
#pragma unroll
        for (int gt = 0; gt < 3; gt++) {
            f32x16 g;
#pragma unroll
            for (int i = 0; i < 16; i++) g[i] = 0.f;
            int p = pb + 32 * gt + l31;
            p = p < 0 ? 0 : (p > 1024 ? 1024 : p);
            const u16* rb = relb + (size_t)p * HD;
#pragma unroll
            for (int ks = 0; ks < 4; ks++) {
                bf16x8 br = *(const bf16x8*)(rb + 16 * ks + 8 * lh);
                g = MFMA(a_q[ks], br, g);
            }
            int jp = 32 * gt + l31;
#pragma unroll
            for (int rg = 0; rg < 16; rg++) {
                int r = (rg & 3) + 8 * (rg >> 2) + rbase;
                Gw[r * 104 + jp] = f2bf(g[rg]);
            }
        }

        // ---- skew gather (wave-private; per-wave DS ordering + compiler waits)
#pragma unroll
        for (int rg = 0; rg < 16; rg++) {
            int r = (rg & 3) + 8 * (rg >> 2) + rbase;
            int j0 = r - l31 + 63;
            S0[rg] += bf2f(Gw[r * 104 + j0]);
            S1[rg] += bf2f(Gw[r * 104 + j0 - 32]);
        }

        // ---- streaming softmax: raw exp, per-lane partial row-sums
#pragma unroll
        for (int rg = 0; rg < 16; rg++) {
            float e0 = __expf(S0[rg]);
            float e1 = __expf(S1[rg]);
            S0[rg] = e0; S1[rg] = e1;
            li[rg] += e0 + e1;
        }

        // ---- P -> LDS bf16 (swizzled, wave-private)
#pragma unroll
        for (int rg = 0; rg < 16; rg++) {
            int r = (rg & 3) + 8 * (rg >> 2) + rbase;
            int ca = l31, cb = l31 + 32;
            Gw[r * 104 + (((ca >> 3) ^ (r & 7)) * 8) + (ca & 7)] = f2bf(S0[rg]);
            Gw[r * 104 + (((cb >> 3) ^ (r & 7)) * 8) + (cb & 7)] = f2bf(S1[rg]);
        }

        // ---- O += P V  (V B-frags straight from global: 8 contiguous t)
        const u16* vb = v_ws + (size_t)bh * HD * TT + m0;
#pragma unroll
        for (int ms = 0; ms < 4; ms++) {
            const int mg = 2 * ms + lh;
            bf16x8 a_p = *(const bf16x8*)&Gw[l31 * 104 + ((mg ^ (l31 & 7)) * 8)];
            bf16x8 b0 = *(const bf16x8*)(vb + (size_t)l31 * TT + mg * 8);
            bf16x8 b1 = *(const bf16x8*)(vb + (size_t)(l31 + 32) * TT + mg * 8);
            O0 = MFMA(a_p, b0, O0);
            O1 = MFMA(a_p, b1, O1);
        }
    }

    // ---- epilogue: reduce li across the 32 lanes holding each row
#pragma unroll
    for (int rg = 0; rg < 16; rg++) {
        float rs = li[rg];
        rs += __shfl_xor(rs, 1);
        rs += __shfl_xor(rs, 2);
        rs += __shfl_xor(rs, 4);
        rs += __shfl_xor(rs, 8);
        rs += __shfl_xor(rs, 16);
        li[rg] = 1.0f / rs;
    }

    // write bf16 [b, t, h*64 + d]
    const int b = bh >> 3, h = bh & 7;
    u16* ob = attn_out + ((size_t)b * TT + n0 + 32 * w) * 512 + h * 64;
#pragma unroll
    for (int rg = 0; rg < 16; rg++) {
        int r = (rg & 3) + 8 * (rg >> 2) + rbase;
        ob[(size_t)r * 512 + l31]      = f2bf(O0[rg] * li[rg]);
        ob[(size_t)r * 512 + l31 + 32] = f2bf(O1[rg] * li[rg]);
    }
}

// ---------------------------------------------------------------------------
// Workspace layout (43 MB total — inside the PROVEN 44 MB envelope).
//   [ 0, 8)  q_wsb
//   [ 8,16)  k_wsb
//   [16,24)  v_wsb
//   [24,32)  x_bf (dead after gemm_qkv)
//   [32,40)  a_wsb (bf16 [b,t,512], written directly by attn)
//   [40,40.5) relb
//   [41,42.5) WT_all    [42.5,43) WoutT
// ---------------------------------------------------------------------------
extern "C" void kernel_launch(void* const* d_in, const int* in_sizes, int n_in,
                              void* d_out, int out_size, void* d_ws, size_t ws_size,
                              hipStream_t stream)
{
    const float* x    = (const float*)d_in[0];
    const float* Wq   = (const float*)d_in[1];
    const float* bq   = (const float*)d_in[2];
    const float* Wkv  = (const float*)d_in[3];
    const float* bkv  = (const float*)d_in[4];
    const float* Wout = (const float*)d_in[5];
    const float* bout = (const float*)d_in[6];
    const float* rel  = (const float*)d_in[7];
    float* out = (float*)d_out;

    char* ws = (char*)d_ws;
    const size_t MB = 1024 * 1024;
    u16*   q_wsb  = (u16*)(ws);                           // 8 MB [b,h,t,d]
    u16*   k_wsb  = (u16*)(ws + 8 * MB);                  // 8 MB [b,h,t,d]
    u16*   v_wsb  = (u16*)(ws + 16 * MB);                 // 8 MB [b,h,d,t]
    u16*   x_bf   = (u16*)(ws + 24 * MB);                 // 8 MB [8192,512]
    u16*   a_wsb  = (u16*)(ws + 32 * MB);                 // 8 MB [b,t,512]
    u16*   relb   = (u16*)(ws + 40 * MB);                 // 128 KB
    u16*   WT_all = (u16*)(ws + 41 * MB);                 // 1.5 MB [1536,512]
    u16*   WoutT  = (u16*)(ws + 42 * MB + 512 * 1024);    // 512 KB [512,512]

    // A: dtype conversions
    cvt_misc<<<(NX4 + NR4 + 255) / 256, 256, 0, stream>>>(x, rel, x_bf, relb);
    cvt_wT<<<256, 256, 0, stream>>>(Wq, Wkv, Wout, WT_all, WT_all + 512 * 512, WoutT);

    // B: fused qkv projection, 64x64/wave (768 blocks = 3/CU)
    gemm_qkv<<<dim3(64, 12), 256, 0, stream>>>(
        x_bf, WT_all, bq, bkv, q_wsb, k_wsb, v_wsb);

    // C: attention, XCD-clustered grid, direct bf16 output (512 blocks = 2/CU)
    attn_mfma<<<dim3(64, 8), 256, 0, stream>>>(
        q_wsb, k_wsb, v_wsb, relb, a_wsb);

    // D: out projection (4096 waves = 16/CU)
    gemm_out<<<dim3(64, 16), 256, 0, stream>>>(a_wsb, WoutT, bout, out);
}

// Round 11
// 278.648 us; speedup vs baseline: 1.2940x; 1.0445x over previous
//
#include <hip/hip_runtime.h>

// Problem constants
#define BB 8
#define TT 1024
#define NH 8
#define HD 64
#define QT 128   // q rows per attention block

typedef unsigned short u16;
typedef __attribute__((ext_vector_type(8))) short bf16x8;
typedef __attribute__((ext_vector_type(16))) float f32x16;

__device__ __forceinline__ float bf2f(u16 s) {
    union { unsigned u; float f; } v; v.u = ((unsigned)s) << 16; return v.f;
}
__device__ __forceinline__ u16 f2bf(float f) {
    union { float f; unsigned u; } v; v.f = f;
    unsigned r = (v.u + 0x7FFFu + ((v.u >> 16) & 1u)) >> 16;
    return (u16)r;
}
__device__ __forceinline__ float bperm(int byte_idx, float v) {
    union { float f; int i; } a; a.f = v;
    union { int i; float f; } b;
    b.i = __builtin_amdgcn_ds_bpermute(byte_idx, a.i);
    return b.f;
}

#define MFMA(a, b, c) __builtin_amdgcn_mfma_f32_32x32x16_bf16((a), (b), (c), 0, 0, 0)

// ---------------------------------------------------------------------------
// Flat fp32 -> bf16 for x (4,194,304 elems) and rel_emb (65,600 elems).
// ---------------------------------------------------------------------------
#define NX4 1048576   // x float4 chunks
#define NR4 16400     // rel float4 chunks
__global__ void cvt_misc(const float* __restrict__ x, const float* __restrict__ rel,
                         u16* __restrict__ xb, u16* __restrict__ relb)
{
    size_t i = (size_t)blockIdx.x * 256 + threadIdx.x;
    const float* src; u16* dst;
    if (i < NX4) { src = x; dst = xb; }
    else {
        i -= NX4;
        if (i >= NR4) return;
        src = rel; dst = relb;
    }
    float4 f = *(const float4*)(src + i * 4);
    ushort4 o;
    o.x = f2bf(f.x); o.y = f2bf(f.y); o.z = f2bf(f.z); o.w = f2bf(f.w);
    *(ushort4*)(dst + i * 4) = o;
}

// ---------------------------------------------------------------------------
// Transpose W [512, N] fp32 -> W^T [N, 512] bf16 (Wq, Wkv, Wout in one grid).
// WqT and WkvT are laid out contiguously (WT_all[1536][512]).
// ---------------------------------------------------------------------------
__global__ __launch_bounds__(256) void cvt_wT(
    const float* __restrict__ Wq, const float* __restrict__ Wkv,
    const float* __restrict__ Wout,
    u16* __restrict__ WqT, u16* __restrict__ WkvT, u16* __restrict__ WoutT)
{
    __shared__ float tile[64][65];
    int bid = blockIdx.x;
    const float* W; u16* Wt; int N, kt, ct;
    if (bid < 64)       { W = Wq;   Wt = WqT;   N = 512;  kt = (bid >> 3) * 64; ct = (bid & 7) * 64; }
    else if (bid < 192) { bid -= 64;  W = Wkv;  Wt = WkvT; N = 1024; kt = (bid >> 4) * 64; ct = (bid & 15) * 64; }
    else                { bid -= 192; W = Wout; Wt = WoutT; N = 512;  kt = (bid >> 3) * 64; ct = (bid & 7) * 64; }

    const int tid = threadIdx.x;
#pragma unroll
    for (int i = 0; i < 16; i++) {
        int e = tid + i * 256;
        int r = e >> 6, c = e & 63;
        tile[r][c] = W[(size_t)(kt + r) * N + ct + c];
    }
    __syncthreads();
#pragma unroll
    for (int i = 0; i < 16; i++) {
        int e = tid + i * 256;
        int rr = e >> 6, cc = e & 63;   // output row = original col
        Wt[(size_t)(ct + rr) * 512 + kt + cc] = f2bf(tile[cc][rr]);
    }
}

// ---------------------------------------------------------------------------
// Fused qkv projection (bf16 MFMA, zero LDS), 64x64 per wave (proven R9:
// rest-time 182 -> 158 us vs the 32x64 version). Block = 4 waves in 2x2 ->
// 128x128 tile. Grid (64, 12). MFMA:VMEM = 1:1.
// B given transposed: WT_all[1536][512]. c<512: q scaled 0.125 -> [b,h,t,d];
// 512..1024: k -> [b,h,t,d]; 1024..1536: v TRANSPOSED -> [b,h,d,t].
// ---------------------------------------------------------------------------
__global__ __launch_bounds__(256) void gemm_qkv(
    const u16* __restrict__ A, const u16* __restrict__ Bt,
    const float* __restrict__ bq, const float* __restrict__ bkv,
    u16* __restrict__ oq, u16* __restrict__ ok, u16* __restrict__ ov)
{
    const int tid = threadIdx.x;
    const int lane = tid & 63, w = tid >> 6;
    const int l31 = lane & 31, lh = lane >> 5;
    const int wr = w & 1, wc = w >> 1;
    const int row0 = blockIdx.x * 128 + 64 * wr;
    const int c0g  = blockIdx.y * 128 + 64 * wc;

    const u16* ap0 = A  + (size_t)(row0 + l31) * 512 + 8 * lh;
    const u16* ap1 = ap0 + (size_t)32 * 512;
    const u16* bp0 = Bt + (size_t)(c0g + l31) * 512 + 8 * lh;
    const u16* bp1 = bp0 + (size_t)32 * 512;

    f32x16 acc[2][2];
#pragma unroll
    for (int i = 0; i < 2; i++)
#pragma unroll
        for (int j = 0; j < 2; j++)
#pragma unroll
            for (int e = 0; e < 16; e++) acc[i][j][e] = 0.f;

#pragma unroll 4
    for (int ks = 0; ks < 32; ks++) {
        bf16x8 a0 = *(const bf16x8*)(ap0 + 16 * ks);
        bf16x8 a1 = *(const bf16x8*)(ap1 + 16 * ks);
        bf16x8 b0 = *(const bf16x8*)(bp0 + 16 * ks);
        bf16x8 b1 = *(const bf16x8*)(bp1 + 16 * ks);
        acc[0][0] = MFMA(a0, b0, acc[0][0]);
        acc[0][1] = MFMA(a0, b1, acc[0][1]);
        acc[1][0] = MFMA(a1, b0, acc[1][0]);
        acc[1][1] = MFMA(a1, b1, acc[1][1]);
    }

    const int rbase = 4 * lh;
#pragma unroll
    for (int ri = 0; ri < 2; ri++) {
#pragma unroll
        for (int ci = 0; ci < 2; ci++) {
            const int r0 = row0 + 32 * ri;
            const int gc = c0g + 32 * ci + l31;
            if (gc < 512) {            // q (scaled)
                const float bv = bq[gc];
                const int h = gc >> 6, d = gc & 63;
#pragma unroll
                for (int rg = 0; rg < 16; rg++) {
                    int gr = r0 + (rg & 3) + 8 * (rg >> 2) + rbase;
                    int b = gr >> 10, t = gr & 1023;
                    oq[(((size_t)b * NH + h) * TT + t) * HD + d] =
                        f2bf((acc[ri][ci][rg] + bv) * 0.125f);
                }
            } else if (gc < 1024) {    // k
                const float bv = bkv[gc - 512];
                const int h = (gc - 512) >> 6, d = gc & 63;
#pragma unroll
                for (int rg = 0; rg < 16; rg++) {
                    int gr = r0 + (rg & 3) + 8 * (rg >> 2) + rbase;
                    int b = gr >> 10, t = gr & 1023;
                    ok[(((size_t)b * NH + h) * TT + t) * HD + d] =
                        f2bf(acc[ri][ci][rg] + bv);
                }
            } else {                   // v, transposed [b,h,d,t]
                const float bv = bkv[gc - 512];
                const int vcol = gc - 1024;
                const int h = vcol >> 6, d = vcol & 63;
                const int b = r0 >> 10;
                const int t0 = (r0 & 1023) + rbase;
                size_t base = (((size_t)b * NH + h) * HD + d) * TT;
#pragma unroll
                for (int g = 0; g < 4; g++) {
                    ushort4 p;
                    p.x = f2bf(acc[ri][ci][4 * g + 0] + bv);
                    p.y = f2bf(acc[ri][ci][4 * g + 1] + bv);
                    p.z = f2bf(acc[ri][ci][4 * g + 2] + bv);
                    p.w = f2bf(acc[ri][ci][4 * g + 3] + bv);
                    *(ushort4*)&ov[base + t0 + 8 * g] = p;
                }
            }
        }
    }
}

// ---------------------------------------------------------------------------
// Out projection: out = a[8192,512] @ Wout + bout, fp32 result.
// R11: wave = 32 rows x 64 cols (2 accs, MFMA:VMEM 2:3 vs old 1:2).
// Block = 4 waves stacked along M (shared B-frag addresses, L1-hot).
// Grid (64, 8) = 512 blocks = 2/CU.
// ---------------------------------------------------------------------------
__global__ __launch_bounds__(256) void gemm_out(
    const u16* __restrict__ A, const u16* __restrict__ Bt,
    const float* __restrict__ bias, float* __restrict__ of)
{
    const int tid = threadIdx.x;
    const int lane = tid & 63, w = tid >> 6;
    const int l31 = lane & 31, lh = lane >> 5;
    const int row0 = blockIdx.x * 128 + 32 * w;
    const int c0 = blockIdx.y * 64;

    const u16* ap  = A  + (size_t)(row0 + l31) * 512 + 8 * lh;
    const u16* bp0 = Bt + (size_t)(c0 + l31) * 512 + 8 * lh;
    const u16* bp1 = bp0 + (size_t)32 * 512;

    f32x16 acc0, acc1;
#pragma unroll
    for (int i = 0; i < 16; i++) { acc0[i] = 0.f; acc1[i] = 0.f; }

#pragma unroll 4
    for (int ks = 0; ks < 32; ks++) {
        bf16x8 a  = *(const bf16x8*)(ap  + 16 * ks);
        bf16x8 b0 = *(const bf16x8*)(bp0 + 16 * ks);
        bf16x8 b1 = *(const bf16x8*)(bp1 + 16 * ks);
        acc0 = MFMA(a, b0, acc0);
        acc1 = MFMA(a, b1, acc1);
    }

    const int rbase = 4 * lh;
    const float bv0 = bias[c0 + l31];
    const float bv1 = bias[c0 + 32 + l31];
#pragma unroll
    for (int rg = 0; rg < 16; rg++) {
        int gr = row0 + (rg & 3) + 8 * (rg >> 2) + rbase;
        of[(size_t)gr * 512 + c0 + l31]      = acc0[rg] + bv0;
        of[(size_t)gr * 512 + c0 + 32 + l31] = acc1[rg] + bv1;
    }
}

// ---------------------------------------------------------------------------
// MFMA flash attention, rel-pos skew via ds_bpermute, barrier-free.
// Grid (64, 8): bx = bh (XCD-clustered, proven R8: FETCH 70->16 MB), by = nt.
// Block: 256 = 4 waves; wave w owns q-rows [32w,32w+32).
// R11: the G-band LDS round-trip (48 f2bf + 48 ds_write + 32 ds_read per
// tile, R10's longest dependency chain) is replaced by register shuffles:
// G[r][j] produced by the gt-MFMA lives at (lane = 32*lh + (j&31), reg rg)
// with the SAME r as the consumer's (rg,lh) -> one ds_bpermute per reg per
// gt (idx = 32*lh + ((r-l31+31)&31)), select g-tile by (r>l31):
//   gt0 -> S1 (r<=l31), gt1 -> S0 (r<=l31) + S1 (r>l31), gt2 -> S0 (r>l31).
// g stays transient (no extra registers). G stays fp32 (skips bf16 trip).
// NO __launch_bounds__ min-waves (R9: forced 3 waves/SIMD -> scratch spills).
// LDS: per-wave 32x104 u16 P buffer (proven stride; R9's stride change
// tripled conflicts). 26.6 KB/block.
// ---------------------------------------------------------------------------
__global__ __launch_bounds__(256) void attn_mfma(
    const u16* __restrict__ q_ws, const u16* __restrict__ k_ws,
    const u16* __restrict__ v_ws, const u16* __restrict__ relb,
    u16* __restrict__ attn_out)
{
    __shared__ __align__(16) u16 GPs[4][32 * 104];   // per-wave P tile

    const int tid  = threadIdx.x;
    const int lane = tid & 63;
    const int w    = tid >> 6;
    const int l31  = lane & 31;
    const int lh   = lane >> 5;
    const int bh   = blockIdx.x;
    const int n0   = blockIdx.y * QT;

    // Q A-fragments (rows n0+32w+l31), held in registers for all 16 m-tiles
    bf16x8 a_q[4];
    {
        const u16* qp = q_ws + (((size_t)bh * TT) + n0 + 32 * w + l31) * HD + 8 * lh;
#pragma unroll
        for (int ks = 0; ks < 4; ks++)
            a_q[ks] = *(const bf16x8*)(qp + 16 * ks);
    }

    f32x16 O0, O1;
    float li[16];
#pragma unroll
    for (int i = 0; i < 16; i++) { O0[i] = 0.f; O1[i] = 0.f; li[i] = 0.f; }

    u16* Gw = GPs[w];
    const int rbase = 4 * lh;

    for (int mt = 0; mt < 16; mt++) {
        const int m0 = mt * 64;
        const u16* kb = k_ws + ((size_t)bh * TT + m0) * HD;

        // ---- S = Q K^T  (B-frags straight from global: 8 contiguous d)
        f32x16 S0, S1;
#pragma unroll
        for (int i = 0; i < 16; i++) { S0[i] = 0.f; S1[i] = 0.f; }
#pragma unroll
        for (int ks = 0; ks < 4; ks++) {
            const int doff = 16 * ks + 8 * lh;
            bf16x8 b0 = *(const bf16x8*)(kb + (size_t)l31 * HD + doff);
            bf16x8 b1 = *(const bf16x8*)(kb + (size_t)(l31 + 32) * HD + doff);
            S0 = MFMA(a_q[ks], b0, S0);
            S1 = MFMA(a_q[ks], b1, S1);
        }

        // ---- G = Q R^T (3 col-tiles); skew-accumulate via ds_bpermute
        const int pb = n0 - m0 + 449 + 32 * w;
#pragma unroll
        for (int gt = 0; gt < 3; gt++) {
            f32x16 g;
#pragma unroll
            for (int i = 0; i < 16; i++) g[i] = 0.f;
            int p = pb + 32 * gt + l31;
            p = p < 0 ? 0 : (p > 1024 ? 1024 : p);
            const u16* rb = relb + (size_t)p * HD;
#pragma unroll
            for (int ks = 0; ks < 4; ks++) {
                bf16x8 br = *(const bf16x8*)(rb + 16 * ks + 8 * lh);
                g = MFMA(a_q[ks], br, g);
            }
#pragma unroll
            for (int rg = 0; rg < 16; rg++) {
                int r = (rg & 3) + 8 * (rg >> 2) + rbase;
                int bidx = (((lh << 5) | ((r - l31 + 31) & 31))) << 2;
                float v = bperm(bidx, g[rg]);
                bool hi = r > l31;
                if (gt == 0)      { S1[rg] += hi ? 0.f : v; }
                else if (gt == 1) { S0[rg] += hi ? 0.f : v; S1[rg] += hi ? v : 0.f; }
                else              { S0[rg] += hi ? v : 0.f; }
            }
        }

        // ---- streaming softmax: raw exp, per-lane partial row-sums
#pragma unroll
        for (int rg = 0; rg < 16; rg++) {
            float e0 = __expf(S0[rg]);
            float e1 = __expf(S1[rg]);
            S0[rg] = e0; S1[rg] = e1;
            li[rg] += e0 + e1;
        }

        // ---- P -> LDS bf16 (swizzled, wave-private; per-wave DS ordering)
#pragma unroll
        for (int rg = 0; rg < 16; rg++) {
            int r = (rg & 3) + 8 * (rg >> 2) + rbase;
            int ca = l31, cb = l31 + 32;
            Gw[r * 104 + (((ca >> 3) ^ (r & 7)) * 8) + (ca & 7)] = f2bf(S0[rg]);
            Gw[r * 104 + (((cb >> 3) ^ (r & 7)) * 8) + (cb & 7)] = f2bf(S1[rg]);
        }

        // ---- O += P V  (V B-frags straight from global: 8 contiguous t)
        const u16* vb = v_ws + (size_t)bh * HD * TT + m0;
#pragma unroll
        for (int ms = 0; ms < 4; ms++) {
            const int mg = 2 * ms + lh;
            bf16x8 a_p = *(const bf16x8*)&Gw[l31 * 104 + ((mg ^ (l31 & 7)) * 8)];
            bf16x8 b0 = *(const bf16x8*)(vb + (size_t)l31 * TT + mg * 8);
            bf16x8 b1 = *(const bf16x8*)(vb + (size_t)(l31 + 32) * TT + mg * 8);
            O0 = MFMA(a_p, b0, O0);
            O1 = MFMA(a_p, b1, O1);
        }
    }

    // ---- epilogue: reduce li across the 32 lanes holding each row
#pragma unroll
    for (int rg = 0; rg < 16; rg++) {
        float rs = li[rg];
        rs += __shfl_xor(rs, 1);
        rs += __shfl_xor(rs, 2);
        rs += __shfl_xor(rs, 4);
        rs += __shfl_xor(rs, 8);
        rs += __shfl_xor(rs, 16);
        li[rg] = 1.0f / rs;
    }

    // write bf16 [b, t, h*64 + d]
    const int b = bh >> 3, h = bh & 7;
    u16* ob = attn_out + ((size_t)b * TT + n0 + 32 * w) * 512 + h * 64;
#pragma unroll
    for (int rg = 0; rg < 16; rg++) {
        int r = (rg & 3) + 8 * (rg >> 2) + rbase;
        ob[(size_t)r * 512 + l31]      = f2bf(O0[rg] * li[rg]);
        ob[(size_t)r * 512 + l31 + 32] = f2bf(O1[rg] * li[rg]);
    }
}

// ---------------------------------------------------------------------------
// Workspace layout (43 MB total — inside the PROVEN 44 MB envelope).
//   [ 0, 8)  q_wsb
//   [ 8,16)  k_wsb
//   [16,24)  v_wsb
//   [24,32)  x_bf (dead after gemm_qkv)
//   [32,40)  a_wsb (bf16 [b,t,512], written directly by attn)
//   [40,40.5) relb
//   [41,42.5) WT_all    [42.5,43) WoutT
// ---------------------------------------------------------------------------
extern "C" void kernel_launch(void* const* d_in, const int* in_sizes, int n_in,
                              void* d_out, int out_size, void* d_ws, size_t ws_size,
                              hipStream_t stream)
{
    const float* x    = (const float*)d_in[0];
    const float* Wq   = (const float*)d_in[1];
    const float* bq   = (const float*)d_in[2];
    const float* Wkv  = (const float*)d_in[3];
    const float* bkv  = (const float*)d_in[4];
    const float* Wout = (const float*)d_in[5];
    const float* bout = (const float*)d_in[6];
    const float* rel  = (const float*)d_in[7];
    float* out = (float*)d_out;

    char* ws = (char*)d_ws;
    const size_t MB = 1024 * 1024;
    u16*   q_wsb  = (u16*)(ws);                           // 8 MB [b,h,t,d]
    u16*   k_wsb  = (u16*)(ws + 8 * MB);                  // 8 MB [b,h,t,d]
    u16*   v_wsb  = (u16*)(ws + 16 * MB);                 // 8 MB [b,h,d,t]
    u16*   x_bf   = (u16*)(ws + 24 * MB);                 // 8 MB [8192,512]
    u16*   a_wsb  = (u16*)(ws + 32 * MB);                 // 8 MB [b,t,512]
    u16*   relb   = (u16*)(ws + 40 * MB);                 // 128 KB
    u16*   WT_all = (u16*)(ws + 41 * MB);                 // 1.5 MB [1536,512]
    u16*   WoutT  = (u16*)(ws + 42 * MB + 512 * 1024);    // 512 KB [512,512]

    // A: dtype conversions
    cvt_misc<<<(NX4 + NR4 + 255) / 256, 256, 0, stream>>>(x, rel, x_bf, relb);
    cvt_wT<<<256, 256, 0, stream>>>(Wq, Wkv, Wout, WT_all, WT_all + 512 * 512, WoutT);

    // B: fused qkv projection, 64x64/wave (768 blocks = 3/CU)
    gemm_qkv<<<dim3(64, 12), 256, 0, stream>>>(
        x_bf, WT_all, bq, bkv, q_wsb, k_wsb, v_wsb);

    // C: attention, XCD-clustered grid, bpermute skew (512 blocks = 2/CU)
    attn_mfma<<<dim3(64, 8), 256, 0, stream>>>(
        q_wsb, k_wsb, v_wsb, relb, a_wsb);

    // D: out projection, 32x64/wave (512 blocks = 2/CU)
    gemm_out<<<dim3(64, 8), 256, 0, stream>>>(a_wsb, WoutT, bout, out);
}

// Round 12
// 274.469 us; speedup vs baseline: 1.3137x; 1.0152x over previous
//
#include <hip/hip_runtime.h>

// Problem constants
#define BB 8
#define TT 1024
#define NH 8
#define HD 64
#define QT 128   // q rows per attention block

typedef unsigned short u16;
typedef __attribute__((ext_vector_type(8))) short bf16x8;
typedef __attribute__((ext_vector_type(16))) float f32x16;

__device__ __forceinline__ float bf2f(u16 s) {
    union { unsigned u; float f; } v; v.u = ((unsigned)s) << 16; return v.f;
}
__device__ __forceinline__ u16 f2bf(float f) {
    union { float f; unsigned u; } v; v.f = f;
    unsigned r = (v.u + 0x7FFFu + ((v.u >> 16) & 1u)) >> 16;
    return (u16)r;
}
__device__ __forceinline__ float bperm(int byte_idx, float v) {
    union { float f; int i; } a; a.f = v;
    union { int i; float f; } b;
    b.i = __builtin_amdgcn_ds_bpermute(byte_idx, a.i);
    return b.f;
}

#define MFMA(a, b, c) __builtin_amdgcn_mfma_f32_32x32x16_bf16((a), (b), (c), 0, 0, 0)

// ---------------------------------------------------------------------------
// Flat fp32 -> bf16 for x (4,194,304 elems) and rel_emb (65,600 elems).
// ---------------------------------------------------------------------------
#define NX4 1048576   // x float4 chunks
#define NR4 16400     // rel float4 chunks
__global__ void cvt_misc(const float* __restrict__ x, const float* __restrict__ rel,
                         u16* __restrict__ xb, u16* __restrict__ relb)
{
    size_t i = (size_t)blockIdx.x * 256 + threadIdx.x;
    const float* src; u16* dst;
    if (i < NX4) { src = x; dst = xb; }
    else {
        i -= NX4;
        if (i >= NR4) return;
        src = rel; dst = relb;
    }
    float4 f = *(const float4*)(src + i * 4);
    ushort4 o;
    o.x = f2bf(f.x); o.y = f2bf(f.y); o.z = f2bf(f.z); o.w = f2bf(f.w);
    *(ushort4*)(dst + i * 4) = o;
}

// ---------------------------------------------------------------------------
// Transpose W [512, N] fp32 -> W^T [N, 512] bf16 (Wq, Wkv, Wout in one grid).
// WqT and WkvT are laid out contiguously (WT_all[1536][512]).
// ---------------------------------------------------------------------------
__global__ __launch_bounds__(256) void cvt_wT(
    const float* __restrict__ Wq, const float* __restrict__ Wkv,
    const float* __restrict__ Wout,
    u16* __restrict__ WqT, u16* __restrict__ WkvT, u16* __restrict__ WoutT)
{
    __shared__ float tile[64][65];
    int bid = blockIdx.x;
    const float* W; u16* Wt; int N, kt, ct;
    if (bid < 64)       { W = Wq;   Wt = WqT;   N = 512;  kt = (bid >> 3) * 64; ct = (bid & 7) * 64; }
    else if (bid < 192) { bid -= 64;  W = Wkv;  Wt = WkvT; N = 1024; kt = (bid >> 4) * 64; ct = (bid & 15) * 64; }
    else                { bid -= 192; W = Wout; Wt = WoutT; N = 512;  kt = (bid >> 3) * 64; ct = (bid & 7) * 64; }

    const int tid = threadIdx.x;
#pragma unroll
    for (int i = 0; i < 16; i++) {
        int e = tid + i * 256;
        int r = e >> 6, c = e & 63;
        tile[r][c] = W[(size_t)(kt + r) * N + ct + c];
    }
    __syncthreads();
#pragma unroll
    for (int i = 0; i < 16; i++) {
        int e = tid + i * 256;
        int rr = e >> 6, cc = e & 63;   // output row = original col
        Wt[(size_t)(ct + rr) * 512 + kt + cc] = f2bf(tile[cc][rr]);
    }
}

// ---------------------------------------------------------------------------
// Fused qkv projection (bf16 MFMA, zero LDS), 64x64 per wave (proven R9).
// Block = 4 waves in 2x2 -> 128x128 tile. Grid (64, 12). MFMA:VMEM = 1:1.
// B given transposed: WT_all[1536][512]. c<512: q scaled 0.125 -> [b,h,t,d];
// 512..1024: k -> [b,h,t,d]; 1024..1536: v TRANSPOSED -> [b,h,d,t].
// ---------------------------------------------------------------------------
__global__ __launch_bounds__(256) void gemm_qkv(
    const u16* __restrict__ A, const u16* __restrict__ Bt,
    const float* __restrict__ bq, const float* __restrict__ bkv,
    u16* __restrict__ oq, u16* __restrict__ ok, u16* __restrict__ ov)
{
    const int tid = threadIdx.x;
    const int lane = tid & 63, w = tid >> 6;
    const int l31 = lane & 31, lh = lane >> 5;
    const int wr = w & 1, wc = w >> 1;
    const int row0 = blockIdx.x * 128 + 64 * wr;
    const int c0g  = blockIdx.y * 128 + 64 * wc;

    const u16* ap0 = A  + (size_t)(row0 + l31) * 512 + 8 * lh;
    const u16* ap1 = ap0 + (size_t)32 * 512;
    const u16* bp0 = Bt + (size_t)(c0g + l31) * 512 + 8 * lh;
    const u16* bp1 = bp0 + (size_t)32 * 512;

    f32x16 acc[2][2];
#pragma unroll
    for (int i = 0; i < 2; i++)
#pragma unroll
        for (int j = 0; j < 2; j++)
#pragma unroll
            for (int e = 0; e < 16; e++) acc[i][j][e] = 0.f;

#pragma unroll 4
    for (int ks = 0; ks < 32; ks++) {
        bf16x8 a0 = *(const bf16x8*)(ap0 + 16 * ks);
        bf16x8 a1 = *(const bf16x8*)(ap1 + 16 * ks);
        bf16x8 b0 = *(const bf16x8*)(bp0 + 16 * ks);
        bf16x8 b1 = *(const bf16x8*)(bp1 + 16 * ks);
        acc[0][0] = MFMA(a0, b0, acc[0][0]);
        acc[0][1] = MFMA(a0, b1, acc[0][1]);
        acc[1][0] = MFMA(a1, b0, acc[1][0]);
        acc[1][1] = MFMA(a1, b1, acc[1][1]);
    }

    const int rbase = 4 * lh;
#pragma unroll
    for (int ri = 0; ri < 2; ri++) {
#pragma unroll
        for (int ci = 0; ci < 2; ci++) {
            const int r0 = row0 + 32 * ri;
            const int gc = c0g + 32 * ci + l31;
            if (gc < 512) {            // q (scaled)
                const float bv = bq[gc];
                const int h = gc >> 6, d = gc & 63;
#pragma unroll
                for (int rg = 0; rg < 16; rg++) {
                    int gr = r0 + (rg & 3) + 8 * (rg >> 2) + rbase;
                    int b = gr >> 10, t = gr & 1023;
                    oq[(((size_t)b * NH + h) * TT + t) * HD + d] =
                        f2bf((acc[ri][ci][rg] + bv) * 0.125f);
                }
            } else if (gc < 1024) {    // k
                const float bv = bkv[gc - 512];
                const int h = (gc - 512) >> 6, d = gc & 63;
#pragma unroll
                for (int rg = 0; rg < 16; rg++) {
                    int gr = r0 + (rg & 3) + 8 * (rg >> 2) + rbase;
                    int b = gr >> 10, t = gr & 1023;
                    ok[(((size_t)b * NH + h) * TT + t) * HD + d] =
                        f2bf(acc[ri][ci][rg] + bv);
                }
            } else {                   // v, transposed [b,h,d,t]
                const float bv = bkv[gc - 512];
                const int vcol = gc - 1024;
                const int h = vcol >> 6, d = vcol & 63;
                const int b = r0 >> 10;
                const int t0 = (r0 & 1023) + rbase;
                size_t base = (((size_t)b * NH + h) * HD + d) * TT;
#pragma unroll
                for (int g = 0; g < 4; g++) {
                    ushort4 p;
                    p.x = f2bf(acc[ri][ci][4 * g + 0] + bv);
                    p.y = f2bf(acc[ri][ci][4 * g + 1] + bv);
                    p.z = f2bf(acc[ri][ci][4 * g + 2] + bv);
                    p.w = f2bf(acc[ri][ci][4 * g + 3] + bv);
                    *(ushort4*)&ov[base + t0 + 8 * g] = p;
                }
            }
        }
    }
}

// ---------------------------------------------------------------------------
// Out projection: out = a[8192,512] @ Wout + bout, fp32 result.
// Wave = 32 rows x 64 cols (2 accs). Grid (64, 8) = 512 blocks.
// ---------------------------------------------------------------------------
__global__ __launch_bounds__(256) void gemm_out(
    const u16* __restrict__ A, const u16* __restrict__ Bt,
    const float* __restrict__ bias, float* __restrict__ of)
{
    const int tid = threadIdx.x;
    const int lane = tid & 63, w = tid >> 6;
    const int l31 = lane & 31, lh = lane >> 5;
    const int row0 = blockIdx.x * 128 + 32 * w;
    const int c0 = blockIdx.y * 64;

    const u16* ap  = A  + (size_t)(row0 + l31) * 512 + 8 * lh;
    const u16* bp0 = Bt + (size_t)(c0 + l31) * 512 + 8 * lh;
    const u16* bp1 = bp0 + (size_t)32 * 512;

    f32x16 acc0, acc1;
#pragma unroll
    for (int i = 0; i < 16; i++) { acc0[i] = 0.f; acc1[i] = 0.f; }

#pragma unroll 4
    for (int ks = 0; ks < 32; ks++) {
        bf16x8 a  = *(const bf16x8*)(ap  + 16 * ks);
        bf16x8 b0 = *(const bf16x8*)(bp0 + 16 * ks);
        bf16x8 b1 = *(const bf16x8*)(bp1 + 16 * ks);
        acc0 = MFMA(a, b0, acc0);
        acc1 = MFMA(a, b1, acc1);
    }

    const int rbase = 4 * lh;
    const float bv0 = bias[c0 + l31];
    const float bv1 = bias[c0 + 32 + l31];
#pragma unroll
    for (int rg = 0; rg < 16; rg++) {
        int gr = row0 + (rg & 3) + 8 * (rg >> 2) + rbase;
        of[(size_t)gr * 512 + c0 + l31]      = acc0[rg] + bv0;
        of[(size_t)gr * 512 + c0 + 32 + l31] = acc1[rg] + bv1;
    }
}

// ---------------------------------------------------------------------------
// MFMA flash attention, rel-pos skew via ds_bpermute, barrier-free,
// CROSS-TILE REGISTER PREFETCH (R12).
// Grid (64, 8): bx = bh (XCD-clustered, proven R8), by = nt.
// Block: 256 = 4 waves; wave w owns q-rows [32w,32w+32).
// R12: at 2 waves/SIMD the wave owns 256 VGPRs; ~190 were used -> burn the
// spare on single-buffer rotation: kf[8] (K frags) and rf[12] (rel frags)
// hold tile mt's data at loop top (loaded during tile mt-1, ~2000 cyc of
// flight); consumed by S/G MFMA with no wait. Per tile the VMEM issue order
// is vf (current V) -> kf (next K) -> rf (next rel) so the FIFO vmcnt waits
// are: PV waits vf leaving kf/rf in flight; next S waits kf leaving rf.
// exp+pack covers vf latency. mt=15 prefetch wraps to m0=0 (unused, valid).
// Peak regs ~240 < 256: no occupancy change expected, no spills (watch
// WRITE_SIZE: R9 taught spills show as tens of MB there).
// LDS: per-wave 32x104 u16 P buffer, 26.6 KB/block.
// ---------------------------------------------------------------------------
__global__ __launch_bounds__(256) void attn_mfma(
    const u16* __restrict__ q_ws, const u16* __restrict__ k_ws,
    const u16* __restrict__ v_ws, const u16* __restrict__ relb,
    u16* __restrict__ attn_out)
{
    __shared__ __align__(16) u16 GPs[4][32 * 104];   // per-wave P tile

    const int tid  = threadIdx.x;
    const int lane = tid & 63;
    const int w    = tid >> 6;
    const int l31  = lane & 31;
    const int lh   = lane >> 5;
    const int bh   = blockIdx.x;
    const int n0   = blockIdx.y * QT;

    // Q A-fragments (rows n0+32w+l31), held in registers for all 16 m-tiles
    bf16x8 a_q[4];
    {
        const u16* qp = q_ws + (((size_t)bh * TT) + n0 + 32 * w + l31) * HD + 8 * lh;
#pragma unroll
        for (int ks = 0; ks < 4; ks++)
            a_q[ks] = *(const bf16x8*)(qp + 16 * ks);
    }

    f32x16 O0, O1;
    float li[16];
#pragma unroll
    for (int i = 0; i < 16; i++) { O0[i] = 0.f; O1[i] = 0.f; li[i] = 0.f; }

    u16* Gw = GPs[w];
    const int rbase = 4 * lh;
    const u16* kbase = k_ws + (size_t)bh * TT * HD;
    const u16* vbase = v_ws + (size_t)bh * HD * TT;

    // ---- prefetch buffers: kf = K frags, rf = rel frags for the CURRENT tile
    bf16x8 kf[8], rf[12];
    {
#pragma unroll
        for (int ks = 0; ks < 4; ks++) {
            const int doff = 16 * ks + 8 * lh;
            kf[2 * ks]     = *(const bf16x8*)(kbase + (size_t)l31 * HD + doff);
            kf[2 * ks + 1] = *(const bf16x8*)(kbase + (size_t)(l31 + 32) * HD + doff);
        }
        const int pb = n0 + 449 + 32 * w;
#pragma unroll
        for (int gt = 0; gt < 3; gt++) {
            int p = pb + 32 * gt + l31;
            p = p < 0 ? 0 : (p > 1024 ? 1024 : p);
            const u16* rb = relb + (size_t)p * HD;
#pragma unroll
            for (int ks = 0; ks < 4; ks++)
                rf[4 * gt + ks] = *(const bf16x8*)(rb + 16 * ks + 8 * lh);
        }
    }

    for (int mt = 0; mt < 16; mt++) {
        const int m0 = mt * 64;

        // ---- 1. S = Q K^T from prefetched kf (no VMEM wait on entry)
        f32x16 S0, S1;
#pragma unroll
        for (int i = 0; i < 16; i++) { S0[i] = 0.f; S1[i] = 0.f; }
#pragma unroll
        for (int ks = 0; ks < 4; ks++) {
            S0 = MFMA(a_q[ks], kf[2 * ks], S0);
            S1 = MFMA(a_q[ks], kf[2 * ks + 1], S1);
        }

        // ---- 2. G = Q R^T from prefetched rf; skew-accumulate via bpermute
#pragma unroll
        for (int gt = 0; gt < 3; gt++) {
            f32x16 g;
#pragma unroll
            for (int i = 0; i < 16; i++) g[i] = 0.f;
#pragma unroll
            for (int ks = 0; ks < 4; ks++)
                g = MFMA(a_q[ks], rf[4 * gt + ks], g);
#pragma unroll
            for (int rg = 0; rg < 16; rg++) {
                int r = (rg & 3) + 8 * (rg >> 2) + rbase;
                int bidx = (((lh << 5) | ((r - l31 + 31) & 31))) << 2;
                float v = bperm(bidx, g[rg]);
                bool hi = r > l31;
                if (gt == 0)      { S1[rg] += hi ? 0.f : v; }
                else if (gt == 1) { S0[rg] += hi ? 0.f : v; S1[rg] += hi ? v : 0.f; }
                else              { S0[rg] += hi ? v : 0.f; }
            }
        }

        // ---- 3. VMEM issue block: vf (current V), then kf/rf for tile mt+1
        bf16x8 vf[8];
        {
            const u16* vb = vbase + m0;
#pragma unroll
            for (int ms = 0; ms < 4; ms++) {
                const int mg = 2 * ms + lh;
                vf[2 * ms]     = *(const bf16x8*)(vb + (size_t)l31 * TT + mg * 8);
                vf[2 * ms + 1] = *(const bf16x8*)(vb + (size_t)(l31 + 32) * TT + mg * 8);
            }
        }
        {
            const int m0n = (mt < 15) ? m0 + 64 : 0;   // wrap: valid mem, unused
            const u16* kb = kbase + (size_t)m0n * HD;
#pragma unroll
            for (int ks = 0; ks < 4; ks++) {
                const int doff = 16 * ks + 8 * lh;
                kf[2 * ks]     = *(const bf16x8*)(kb + (size_t)l31 * HD + doff);
                kf[2 * ks + 1] = *(const bf16x8*)(kb + (size_t)(l31 + 32) * HD + doff);
            }
            const int pb = n0 - m0n + 449 + 32 * w;
#pragma unroll
            for (int gt = 0; gt < 3; gt++) {
                int p = pb + 32 * gt + l31;
                p = p < 0 ? 0 : (p > 1024 ? 1024 : p);
                const u16* rb = relb + (size_t)p * HD;
#pragma unroll
                for (int ks = 0; ks < 4; ks++)
                    rf[4 * gt + ks] = *(const bf16x8*)(rb + 16 * ks + 8 * lh);
            }
        }

        // ---- 4. streaming softmax + P pack (covers vf latency)
#pragma unroll
        for (int rg = 0; rg < 16; rg++) {
            float e0 = __expf(S0[rg]);
            float e1 = __expf(S1[rg]);
            S0[rg] = e0; S1[rg] = e1;
            li[rg] += e0 + e1;
        }
#pragma unroll
        for (int rg = 0; rg < 16; rg++) {
            int r = (rg & 3) + 8 * (rg >> 2) + rbase;
            int ca = l31, cb = l31 + 32;
            Gw[r * 104 + (((ca >> 3) ^ (r & 7)) * 8) + (ca & 7)] = f2bf(S0[rg]);
            Gw[r * 104 + (((cb >> 3) ^ (r & 7)) * 8) + (cb & 7)] = f2bf(S1[rg]);
        }

        // ---- 5. O += P V from vf (waits vf only; kf/rf stay in flight)
#pragma unroll
        for (int ms = 0; ms < 4; ms++) {
            const int mg = 2 * ms + lh;
            bf16x8 a_p = *(const bf16x8*)&Gw[l31 * 104 + ((mg ^ (l31 & 7)) * 8)];
            O0 = MFMA(a_p, vf[2 * ms], O0);
            O1 = MFMA(a_p, vf[2 * ms + 1], O1);
        }
    }

    // ---- epilogue: reduce li across the 32 lanes holding each row
#pragma unroll
    for (int rg = 0; rg < 16; rg++) {
        float rs = li[rg];
        rs += __shfl_xor(rs, 1);
        rs += __shfl_xor(rs, 2);
        rs += __shfl_xor(rs, 4);
        rs += __shfl_xor(rs, 8);
        rs += __shfl_xor(rs, 16);
        li[rg] = 1.0f / rs;
    }

    // write bf16 [b, t, h*64 + d]
    const int b = bh >> 3, h = bh & 7;
    u16* ob = attn_out + ((size_t)b * TT + n0 + 32 * w) * 512 + h * 64;
#pragma unroll
    for (int rg = 0; rg < 16; rg++) {
        int r = (rg & 3) + 8 * (rg >> 2) + rbase;
        ob[(size_t)r * 512 + l31]      = f2bf(O0[rg] * li[rg]);
        ob[(size_t)r * 512 + l31 + 32] = f2bf(O1[rg] * li[rg]);
    }
}

// ---------------------------------------------------------------------------
// Workspace layout (43 MB total — inside the PROVEN 44 MB envelope).
//   [ 0, 8)  q_wsb
//   [ 8,16)  k_wsb
//   [16,24)  v_wsb
//   [24,32)  x_bf (dead after gemm_qkv)
//   [32,40)  a_wsb (bf16 [b,t,512], written directly by attn)
//   [40,40.5) relb
//   [41,42.5) WT_all    [42.5,43) WoutT
// ---------------------------------------------------------------------------
extern "C" void kernel_launch(void* const* d_in, const int* in_sizes, int n_in,
                              void* d_out, int out_size, void* d_ws, size_t ws_size,
                              hipStream_t stream)
{
    const float* x    = (const float*)d_in[0];
    const float* Wq   = (const float*)d_in[1];
    const float* bq   = (const float*)d_in[2];
    const float* Wkv  = (const float*)d_in[3];
    const float* bkv  = (const float*)d_in[4];
    const float* Wout = (const float*)d_in[5];
    const float* bout = (const float*)d_in[6];
    const float* rel  = (const float*)d_in[7];
    float* out = (float*)d_out;

    char* ws = (char*)d_ws;
    const size_t MB = 1024 * 1024;
    u16*   q_wsb  = (u16*)(ws);                           // 8 MB [b,h,t,d]
    u16*   k_wsb  = (u16*)(ws + 8 * MB);                  // 8 MB [b,h,t,d]
    u16*   v_wsb  = (u16*)(ws + 16 * MB);                 // 8 MB [b,h,d,t]
    u16*   x_bf   = (u16*)(ws + 24 * MB);                 // 8 MB [8192,512]
    u16*   a_wsb  = (u16*)(ws + 32 * MB);                 // 8 MB [b,t,512]
    u16*   relb   = (u16*)(ws + 40 * MB);                 // 128 KB
    u16*   WT_all = (u16*)(ws + 41 * MB);                 // 1.5 MB [1536,512]
    u16*   WoutT  = (u16*)(ws + 42 * MB + 512 * 1024);    // 512 KB [512,512]

    // A: dtype conversions
    cvt_misc<<<(NX4 + NR4 + 255) / 256, 256, 0, stream>>>(x, rel, x_bf, relb);
    cvt_wT<<<256, 256, 0, stream>>>(Wq, Wkv, Wout, WT_all, WT_all + 512 * 512, WoutT);

    // B: fused qkv projection, 64x64/wave (768 blocks = 3/CU)
    gemm_qkv<<<dim3(64, 12), 256, 0, stream>>>(
        x_bf, WT_all, bq, bkv, q_wsb, k_wsb, v_wsb);

    // C: attention, XCD-clustered, bpermute skew, cross-tile prefetch
    attn_mfma<<<dim3(64, 8), 256, 0, stream>>>(
        q_wsb, k_wsb, v_wsb, relb, a_wsb);

    // D: out projection, 32x64/wave (512 blocks = 2/CU)
    gemm_out<<<dim3(64, 8), 256, 0, stream>>>(a_wsb, WoutT, bout, out);
}